// Round 1
// baseline (13360.706 us; speedup 1.0000x reference)
//
#include <hip/hip_runtime.h>

#define N_NODES 100000
#define N_EDGES 1600000
#define N_GRAPHS 256
#define SEQ 365
#define F_DYN 16
#define H_GNN 64
#define GATES 512
#define EPSV 1e-5f
#define TC 48
#define NCHUNK 8

__device__ __forceinline__ float rl(float v, int l) {
    return __int_as_float(__builtin_amdgcn_readlane(__float_as_int(v), l));
}
__device__ __forceinline__ float sigmoidf_(float x) { return 1.f / (1.f + __expf(-x)); }
__device__ __forceinline__ float tanhf_(float x) { return 1.f - 2.f / (__expf(2.f * x) + 1.f); }

// ---------------- GCN ----------------

__global__ void deg_kernel(const int* __restrict__ ei, float* __restrict__ cnt) {
    int e = blockIdx.x * 256 + threadIdx.x;
    if (e < N_EDGES) atomicAdd(&cnt[ei[N_EDGES + e]], 1.0f);
}

__global__ void dinv_kernel(float* __restrict__ d) {
    int n = blockIdx.x * 256 + threadIdx.x;
    if (n < N_NODES) d[n] = rsqrtf(1.0f + d[n]);
}

template <int K>
__global__ __launch_bounds__(256) void mm_kernel(const float* __restrict__ X,
                                                 const float* __restrict__ W,
                                                 float* __restrict__ P) {
    __shared__ float Xs[64 * K];
    __shared__ float Ws[K * 64];
    int tid = threadIdx.x, bm = blockIdx.x;
#pragma unroll
    for (int i = 0; i < (K * 64 / 4) / 256; i++)
        ((float4*)Ws)[i * 256 + tid] = ((const float4*)W)[i * 256 + tid];
#pragma unroll
    for (int i = 0; i < (64 * K / 4) / 256; i++) {
        int f4 = i * 256 + tid;
        int r = (f4 * 4) / K, c = (f4 * 4) % K;
        int row = bm * 64 + r;
        float4 v = make_float4(0.f, 0.f, 0.f, 0.f);
        if (row < N_NODES) v = *(const float4*)(X + (size_t)row * K + c);
        ((float4*)Xs)[f4] = v;
    }
    __syncthreads();
    int f = tid & 63, nz = tid >> 6;
    float acc[16];
#pragma unroll
    for (int i = 0; i < 16; i++) acc[i] = 0.f;
    for (int k = 0; k < K; k++) {
        float wv = Ws[k * 64 + f];
#pragma unroll
        for (int ni = 0; ni < 16; ni++) acc[ni] += Xs[(nz * 16 + ni) * K + k] * wv;
    }
#pragma unroll
    for (int ni = 0; ni < 16; ni++) {
        int row = bm * 64 + nz * 16 + ni;
        if (row < N_NODES) P[(size_t)row * 64 + f] = acc[ni];
    }
}

__global__ void agg_kernel(const int* __restrict__ ei, const float* __restrict__ dinv,
                           const float* __restrict__ P, float* __restrict__ G) {
    int gid = blockIdx.x * 256 + threadIdx.x;  // 6.4M exact
    int e = gid >> 2, q = gid & 3;
    int src = ei[e], dst = ei[N_EDGES + e];
    float w = dinv[src] * dinv[dst];
    const float4* Ps = (const float4*)(P + (size_t)src * 64 + q * 16);
    float* Gd = G + (size_t)dst * 64 + q * 16;
#pragma unroll
    for (int i = 0; i < 4; i++) {
        float4 v = Ps[i];
        atomicAdd(Gd + i * 4 + 0, v.x * w);
        atomicAdd(Gd + i * 4 + 1, v.y * w);
        atomicAdd(Gd + i * 4 + 2, v.z * w);
        atomicAdd(Gd + i * 4 + 3, v.w * w);
    }
}

__global__ void post_kernel(const float* __restrict__ G, const float* __restrict__ P,
                            const float* __restrict__ dinv, const float* __restrict__ bias,
                            const float* __restrict__ gm, const float* __restrict__ bt,
                            const float* __restrict__ mn, const float* __restrict__ vr,
                            float* __restrict__ Ho) {
    int gid = blockIdx.x * 256 + threadIdx.x;  // 6.4M exact
    int n = gid >> 6, f = gid & 63;
    float di = dinv[n];
    float v = G[gid] + P[gid] * di * di + bias[f];
    float s = gm[f] * rsqrtf(vr[f] + EPSV);
    v = (v - mn[f]) * s + bt[f];
    Ho[gid] = fmaxf(v, 0.f);
}

__global__ __launch_bounds__(256) void pool_kernel(const float* __restrict__ H,
                                                   const int* __restrict__ batch,
                                                   float* __restrict__ emb) {
    int g = blockIdx.x, tid = threadIdx.x;
    int lo = 0, hi = N_NODES;
    while (lo < hi) { int mid = (lo + hi) >> 1; if (batch[mid] < g) lo = mid + 1; else hi = mid; }
    int start = lo;
    hi = N_NODES;
    while (lo < hi) { int mid = (lo + hi) >> 1; if (batch[mid] < g + 1) lo = mid + 1; else hi = mid; }
    int end = lo;
    int f = tid & 63, p = tid >> 6;
    float acc = 0.f;
    for (int n = start + p; n < end; n += 4) acc += H[(size_t)n * 64 + f];
    __shared__ float sm[4][64];
    sm[p][f] = acc;
    __syncthreads();
    if (p == 0) {
        float tot = sm[0][f] + sm[1][f] + sm[2][f] + sm[3][f];
        emb[g * 64 + f] = tot / fmaxf((float)(end - start), 1.f);
    }
}

// ---------------- LSTM ----------------

__global__ __launch_bounds__(512, 2) void lstm0_kernel(const float* __restrict__ dyn,
                                                       const float* __restrict__ Wih,
                                                       const float* __restrict__ Whh,
                                                       const float* __restrict__ bih,
                                                       const float* __restrict__ bhh,
                                                       float* __restrict__ H0) {
    int b = blockIdx.x, g = threadIdx.x, lane = g & 63;
    float w[128];
    const float4* W4 = (const float4*)(Whh + (size_t)g * 128);
#pragma unroll
    for (int i = 0; i < 32; i++) {
        float4 v = W4[i];
        w[4 * i] = v.x; w[4 * i + 1] = v.y; w[4 * i + 2] = v.z; w[4 * i + 3] = v.w;
    }
    float wx[16];
    const float4* Wx4 = (const float4*)(Wih + (size_t)g * 16);
#pragma unroll
    for (int i = 0; i < 4; i++) {
        float4 v = Wx4[i];
        wx[4 * i] = v.x; wx[4 * i + 1] = v.y; wx[4 * i + 2] = v.z; wx[4 * i + 3] = v.w;
    }
    float bias = bih[g] + bhh[g];
    __shared__ float h_s[128];
    __shared__ float z_s[512];
    float c = 0.f;
    if (g < 128) h_s[g] = 0.f;
    __syncthreads();
    const float* xb = dyn + (size_t)b * SEQ * F_DYN;
    float* Hb = H0 + (size_t)b * SEQ * 128;
    float xtv = xb[lane & 15];
    for (int t = 0; t < SEQ; t++) {
        float xtn = (t + 1 < SEQ) ? xb[(t + 1) * 16 + (lane & 15)] : 0.f;
        float hva = h_s[lane], hvb = h_s[64 + lane];
        float a0 = bias, a1 = 0.f, a2 = 0.f, a3 = 0.f;
#pragma unroll
        for (int k = 0; k < 16; k += 4) {
            a0 += wx[k] * rl(xtv, k);
            a1 += wx[k + 1] * rl(xtv, k + 1);
            a2 += wx[k + 2] * rl(xtv, k + 2);
            a3 += wx[k + 3] * rl(xtv, k + 3);
        }
#pragma unroll
        for (int k = 0; k < 64; k += 4) {
            a0 += w[k] * rl(hva, k);
            a1 += w[k + 1] * rl(hva, k + 1);
            a2 += w[k + 2] * rl(hva, k + 2);
            a3 += w[k + 3] * rl(hva, k + 3);
        }
#pragma unroll
        for (int k = 0; k < 64; k += 4) {
            a0 += w[64 + k] * rl(hvb, k);
            a1 += w[65 + k] * rl(hvb, k + 1);
            a2 += w[66 + k] * rl(hvb, k + 2);
            a3 += w[67 + k] * rl(hvb, k + 3);
        }
        z_s[g] = (a0 + a1) + (a2 + a3);
        __syncthreads();
        if (g < 128) {
            float zi = z_s[g], zf = z_s[g + 128], zg = z_s[g + 256], zo = z_s[g + 384];
            float ii = sigmoidf_(zi), ff = sigmoidf_(zf), gg = tanhf_(zg), oo = sigmoidf_(zo);
            c = ff * c + ii * gg;
            float hn = oo * tanhf_(c);
            h_s[g] = hn;
            Hb[t * 128 + g] = hn;
        }
        __syncthreads();
        xtv = xtn;
    }
}

__global__ __launch_bounds__(256, 2) void gemm_a1_kernel(const float* __restrict__ H0,
                                                         const float* __restrict__ B,
                                                         const float* __restrict__ bih,
                                                         const float* __restrict__ bhh,
                                                         float* __restrict__ A1c, int t0) {
    __shared__ float As[64][132];
    __shared__ float Bs[64][132];
    int tid = threadIdx.x;
    int bm = blockIdx.x, bn = blockIdx.y;
    int tx = tid & 15, ty = tid >> 4;
    float acc[8][8];
#pragma unroll
    for (int i = 0; i < 8; i++)
#pragma unroll
        for (int j = 0; j < 8; j++) acc[i][j] = 0.f;
    for (int kc = 0; kc < 128; kc += 64) {
#pragma unroll
        for (int i = 0; i < 8; i++) {
            int f4 = i * 256 + tid;       // 0..2047
            int r = f4 >> 4;              // 0..127
            int cc = (f4 & 15) * 4;       // 0..60
            int row = bm * 128 + r;
            int bb = row / TC, tl = row - bb * TC;
            int t = t0 + tl;
            float4 v = make_float4(0.f, 0.f, 0.f, 0.f);
            if (t < SEQ) v = *(const float4*)(H0 + ((size_t)bb * SEQ + t) * 128 + kc + cc);
            As[cc + 0][r] = v.x; As[cc + 1][r] = v.y; As[cc + 2][r] = v.z; As[cc + 3][r] = v.w;
            float4 u = *(const float4*)(B + (size_t)(bn * 128 + r) * 128 + kc + cc);
            Bs[cc + 0][r] = u.x; Bs[cc + 1][r] = u.y; Bs[cc + 2][r] = u.z; Bs[cc + 3][r] = u.w;
        }
        __syncthreads();
#pragma unroll
        for (int k = 0; k < 64; k++) {
            float av[8], bv[8];
            *(float4*)&av[0] = *(const float4*)&As[k][ty * 8];
            *(float4*)&av[4] = *(const float4*)&As[k][ty * 8 + 4];
            *(float4*)&bv[0] = *(const float4*)&Bs[k][tx * 8];
            *(float4*)&bv[4] = *(const float4*)&Bs[k][tx * 8 + 4];
#pragma unroll
            for (int i = 0; i < 8; i++)
#pragma unroll
                for (int j = 0; j < 8; j++) acc[i][j] += av[i] * bv[j];
        }
        __syncthreads();
    }
    float bb8[8];
#pragma unroll
    for (int j = 0; j < 8; j++) {
        int col = bn * 128 + tx * 8 + j;
        bb8[j] = bih[col] + bhh[col];
    }
#pragma unroll
    for (int i = 0; i < 8; i++) {
        int row = bm * 128 + ty * 8 + i;
        float4 o0 = make_float4(acc[i][0] + bb8[0], acc[i][1] + bb8[1], acc[i][2] + bb8[2], acc[i][3] + bb8[3]);
        float4 o1 = make_float4(acc[i][4] + bb8[4], acc[i][5] + bb8[5], acc[i][6] + bb8[6], acc[i][7] + bb8[7]);
        *(float4*)(A1c + (size_t)row * GATES + bn * 128 + tx * 8) = o0;
        *(float4*)(A1c + (size_t)row * GATES + bn * 128 + tx * 8 + 4) = o1;
    }
}

__global__ __launch_bounds__(512, 2) void lstm1_kernel(const float* __restrict__ A1c,
                                                       const float* __restrict__ Whh,
                                                       float* __restrict__ state,
                                                       float* __restrict__ rnn, int t0, int tc) {
    int b = blockIdx.x, g = threadIdx.x, lane = g & 63;
    float w[128];
    const float4* W4 = (const float4*)(Whh + (size_t)g * 128);
#pragma unroll
    for (int i = 0; i < 32; i++) {
        float4 v = W4[i];
        w[4 * i] = v.x; w[4 * i + 1] = v.y; w[4 * i + 2] = v.z; w[4 * i + 3] = v.w;
    }
    __shared__ float h_s[128];
    __shared__ float z_s[512];
    float c = 0.f;
    if (g < 128) {
        if (t0 == 0) {
            h_s[g] = 0.f;
        } else {
            h_s[g] = state[b * 128 + g];
            c = state[N_GRAPHS * 128 + b * 128 + g];
        }
    }
    __syncthreads();
    const float* Ab = A1c + (size_t)b * TC * GATES;
    float a_cur = Ab[g];
    float hn = 0.f;
    for (int tl = 0; tl < tc; tl++) {
        float a_next = (tl + 1 < tc) ? Ab[(tl + 1) * GATES + g] : 0.f;
        float hva = h_s[lane], hvb = h_s[64 + lane];
        float a0 = a_cur, a1 = 0.f, a2 = 0.f, a3 = 0.f;
#pragma unroll
        for (int k = 0; k < 64; k += 4) {
            a0 += w[k] * rl(hva, k);
            a1 += w[k + 1] * rl(hva, k + 1);
            a2 += w[k + 2] * rl(hva, k + 2);
            a3 += w[k + 3] * rl(hva, k + 3);
        }
#pragma unroll
        for (int k = 0; k < 64; k += 4) {
            a0 += w[64 + k] * rl(hvb, k);
            a1 += w[65 + k] * rl(hvb, k + 1);
            a2 += w[66 + k] * rl(hvb, k + 2);
            a3 += w[67 + k] * rl(hvb, k + 3);
        }
        z_s[g] = (a0 + a1) + (a2 + a3);
        __syncthreads();
        if (g < 128) {
            float zi = z_s[g], zf = z_s[g + 128], zg = z_s[g + 256], zo = z_s[g + 384];
            float ii = sigmoidf_(zi), ff = sigmoidf_(zf), gg = tanhf_(zg), oo = sigmoidf_(zo);
            c = ff * c + ii * gg;
            hn = oo * tanhf_(c);
            h_s[g] = hn;
        }
        __syncthreads();
        a_cur = a_next;
    }
    if (g < 128) {
        state[b * 128 + g] = hn;
        state[N_GRAPHS * 128 + b * 128 + g] = c;
        if (t0 + tc == SEQ) rnn[b * 128 + g] = hn;
    }
}

// ---------------- Head ----------------

__global__ __launch_bounds__(128) void head_kernel(const float* __restrict__ gnn, const float* __restrict__ rnn,
                                                   const float* __restrict__ Wf1, const float* __restrict__ bf1,
                                                   const float* __restrict__ fg, const float* __restrict__ fb,
                                                   const float* __restrict__ fm, const float* __restrict__ fv,
                                                   const float* __restrict__ Wf2, const float* __restrict__ bf2,
                                                   const float* __restrict__ Wo, const float* __restrict__ bo,
                                                   float* __restrict__ out) {
    int b = blockIdx.x, tid = threadIdx.x;
    __shared__ float fused[192];
    __shared__ float x1[128];
    __shared__ float x2[64];
    if (tid < 64) fused[tid] = gnn[b * 64 + tid];
    fused[64 + tid] = rnn[b * 128 + tid];
    __syncthreads();
    float acc = bf1[tid];
    for (int k = 0; k < 192; k++) acc += fused[k] * Wf1[k * 128 + tid];
    float s = fg[tid] * rsqrtf(fv[tid] + EPSV);
    acc = (acc - fm[tid]) * s + fb[tid];
    x1[tid] = fmaxf(acc, 0.f);
    __syncthreads();
    if (tid < 64) {
        float a2 = bf2[tid];
        for (int k = 0; k < 128; k++) a2 += x1[k] * Wf2[k * 64 + tid];
        x2[tid] = fmaxf(a2, 0.f);
    }
    __syncthreads();
    if (tid < 10) {
        float a3 = bo[tid];
        for (int k = 0; k < 64; k++) a3 += x2[k] * Wo[k * 10 + tid];
        out[b * 10 + tid] = a3;
    }
}

extern "C" void kernel_launch(void* const* d_in, const int* in_sizes, int n_in,
                              void* d_out, int out_size, void* d_ws, size_t ws_size,
                              hipStream_t stream) {
    const float* dyn = (const float*)d_in[0];
    const float* xs = (const float*)d_in[1];
    const int* ei = (const int*)d_in[2];
    const int* batch = (const int*)d_in[3];
    const float* Wg1 = (const float*)d_in[4];
    const float* bg1 = (const float*)d_in[5];
    const float* Wg2 = (const float*)d_in[6];
    const float* bg2 = (const float*)d_in[7];
    const float* bn1g = (const float*)d_in[8], *bn1b = (const float*)d_in[9];
    const float* bn1m = (const float*)d_in[10], *bn1v = (const float*)d_in[11];
    const float* bn2g = (const float*)d_in[12], *bn2b = (const float*)d_in[13];
    const float* bn2m = (const float*)d_in[14], *bn2v = (const float*)d_in[15];
    const float* l0Wih = (const float*)d_in[16], *l0Whh = (const float*)d_in[17];
    const float* l0bih = (const float*)d_in[18], *l0bhh = (const float*)d_in[19];
    const float* l1Wih = (const float*)d_in[20], *l1Whh = (const float*)d_in[21];
    const float* l1bih = (const float*)d_in[22], *l1bhh = (const float*)d_in[23];
    const float* Wf1 = (const float*)d_in[24], *bf1 = (const float*)d_in[25];
    const float* fbg = (const float*)d_in[26], *fbb = (const float*)d_in[27];
    const float* fbm = (const float*)d_in[28], *fbv = (const float*)d_in[29];
    const float* Wf2 = (const float*)d_in[30], *bf2 = (const float*)d_in[31];
    const float* Wo = (const float*)d_in[32], *bo = (const float*)d_in[33];
    float* out = (float*)d_out;

    float* ws = (float*)d_ws;
    float* P = ws;                     // 6,400,000
    float* G = P + 6400000;            // 6,400,000
    float* H = G + 6400000;            // 6,400,000
    float* dinv = H + 6400000;         // 100,000
    float* gnn = dinv + 100000;        // 16,384
    float* rnn = gnn + 16384;          // 32,768
    float* st = rnn + 32768;           // 65,536  (h1 ; c1)
    float* H0 = st + 65536;            // 11,962,880
    float* A1c = H0 + 11962880;        // 6,291,456   total ≈ 150.7 MB

    hipMemsetAsync(dinv, 0, N_NODES * sizeof(float), stream);
    hipMemsetAsync(G, 0, (size_t)N_NODES * 64 * sizeof(float), stream);
    deg_kernel<<<(N_EDGES + 255) / 256, 256, 0, stream>>>(ei, dinv);
    dinv_kernel<<<(N_NODES + 255) / 256, 256, 0, stream>>>(dinv);

    mm_kernel<32><<<(N_NODES + 63) / 64, 256, 0, stream>>>(xs, Wg1, P);
    agg_kernel<<<25000, 256, 0, stream>>>(ei, dinv, P, G);
    post_kernel<<<25000, 256, 0, stream>>>(G, P, dinv, bg1, bn1g, bn1b, bn1m, bn1v, H);

    hipMemsetAsync(G, 0, (size_t)N_NODES * 64 * sizeof(float), stream);
    mm_kernel<64><<<(N_NODES + 63) / 64, 256, 0, stream>>>(H, Wg2, P);
    agg_kernel<<<25000, 256, 0, stream>>>(ei, dinv, P, G);
    post_kernel<<<25000, 256, 0, stream>>>(G, P, dinv, bg2, bn2g, bn2b, bn2m, bn2v, H);

    pool_kernel<<<N_GRAPHS, 256, 0, stream>>>(H, batch, gnn);

    lstm0_kernel<<<N_GRAPHS, 512, 0, stream>>>(dyn, l0Wih, l0Whh, l0bih, l0bhh, H0);
    for (int ch = 0; ch < NCHUNK; ch++) {
        int t0 = ch * TC;
        int tc = (SEQ - t0 < TC) ? (SEQ - t0) : TC;
        gemm_a1_kernel<<<dim3(96, 4), 256, 0, stream>>>(H0, l1Wih, l1bih, l1bhh, A1c, t0);
        lstm1_kernel<<<N_GRAPHS, 512, 0, stream>>>(A1c, l1Whh, st, rnn, t0, tc);
    }

    head_kernel<<<N_GRAPHS, 128, 0, stream>>>(gnn, rnn, Wf1, bf1, fbg, fbb, fbm, fbv, Wf2, bf2, Wo, bo, out);
}

// Round 2
// 1835.383 us; speedup vs baseline: 7.2795x; 7.2795x over previous
//
#include <hip/hip_runtime.h>

#define N_NODES 100000
#define N_EDGES 1600000
#define N_GRAPHS 256
#define SEQ 365
#define F_DYN 16
#define H_GNN 64
#define GATES 512
#define EPSV 1e-5f
#define TC 48
#define NCHUNK 8
#define NBLK_SCAN 391   // ceil(100000/256)

__device__ __forceinline__ float rl(float v, int l) {
    return __int_as_float(__builtin_amdgcn_readlane(__float_as_int(v), l));
}
__device__ __forceinline__ float sigmoidf_(float x) { return 1.f / (1.f + __expf(-x)); }
__device__ __forceinline__ float tanhf_(float x) { return 1.f - 2.f / (__expf(2.f * x) + 1.f); }

// ---------------- CSR build (counting sort by dst) ----------------

__global__ void hist_kernel(const int* __restrict__ ei, int* __restrict__ deg) {
    int e = blockIdx.x * 256 + threadIdx.x;
    if (e < N_EDGES) atomicAdd(&deg[ei[N_EDGES + e]], 1);
}

__global__ __launch_bounds__(256) void scan1_kernel(const int* __restrict__ deg, int* __restrict__ bsum) {
    __shared__ int sm[256];
    int n = blockIdx.x * 256 + threadIdx.x;
    sm[threadIdx.x] = (n < N_NODES) ? deg[n] : 0;
    __syncthreads();
    for (int off = 128; off > 0; off >>= 1) {
        if (threadIdx.x < off) sm[threadIdx.x] += sm[threadIdx.x + off];
        __syncthreads();
    }
    if (threadIdx.x == 0) bsum[blockIdx.x] = sm[0];
}

__global__ __launch_bounds__(512) void scan2_kernel(int* __restrict__ bsum) {
    __shared__ int sc[512];
    int tid = threadIdx.x;
    int v = (tid < NBLK_SCAN) ? bsum[tid] : 0;
    sc[tid] = v;
    __syncthreads();
    for (int off = 1; off < 512; off <<= 1) {
        int t = (tid >= off) ? sc[tid - off] : 0;
        __syncthreads();
        sc[tid] += t;
        __syncthreads();
    }
    if (tid < NBLK_SCAN) bsum[tid] = sc[tid] - v;  // exclusive
}

__global__ __launch_bounds__(256) void scan3_kernel(const int* __restrict__ deg, const int* __restrict__ bsum,
                                                    int* __restrict__ offs, int* __restrict__ cursor,
                                                    float* __restrict__ dinv) {
    __shared__ int sc[256];
    int tid = threadIdx.x, n = blockIdx.x * 256 + tid;
    int v = (n < N_NODES) ? deg[n] : 0;
    sc[tid] = v;
    __syncthreads();
    for (int off = 1; off < 256; off <<= 1) {
        int t = (tid >= off) ? sc[tid - off] : 0;
        __syncthreads();
        sc[tid] += t;
        __syncthreads();
    }
    int ex = sc[tid] - v + bsum[blockIdx.x];
    if (n < N_NODES) {
        offs[n] = ex;
        cursor[n] = ex;
        dinv[n] = rsqrtf(1.f + (float)v);
        if (n == N_NODES - 1) offs[N_NODES] = ex + v;
    }
}

__global__ void fill_kernel(const int* __restrict__ ei, const float* __restrict__ dinv,
                            int* __restrict__ cursor, int2* __restrict__ epk) {
    int e = blockIdx.x * 256 + threadIdx.x;
    if (e >= N_EDGES) return;
    int s = ei[e], d = ei[N_EDGES + e];
    int pos = atomicAdd(&cursor[d], 1);
    epk[pos] = make_int2(s, __float_as_int(dinv[s] * dinv[d]));
}

// ---------------- GCN ----------------

template <int K>
__global__ __launch_bounds__(256) void mm_kernel(const float* __restrict__ X,
                                                 const float* __restrict__ W,
                                                 float* __restrict__ P) {
    __shared__ float Xs[64 * K];
    __shared__ float Ws[K * 64];
    int tid = threadIdx.x, bm = blockIdx.x;
#pragma unroll
    for (int i = 0; i < (K * 64 / 4) / 256; i++)
        ((float4*)Ws)[i * 256 + tid] = ((const float4*)W)[i * 256 + tid];
#pragma unroll
    for (int i = 0; i < (64 * K / 4) / 256; i++) {
        int f4 = i * 256 + tid;
        int r = (f4 * 4) / K, c = (f4 * 4) % K;
        int row = bm * 64 + r;
        float4 v = make_float4(0.f, 0.f, 0.f, 0.f);
        if (row < N_NODES) v = *(const float4*)(X + (size_t)row * K + c);
        ((float4*)Xs)[f4] = v;
    }
    __syncthreads();
    int f = tid & 63, nz = tid >> 6;
    float acc[16];
#pragma unroll
    for (int i = 0; i < 16; i++) acc[i] = 0.f;
    for (int k = 0; k < K; k++) {
        float wv = Ws[k * 64 + f];
#pragma unroll
        for (int ni = 0; ni < 16; ni++) acc[ni] += Xs[(nz * 16 + ni) * K + k] * wv;
    }
#pragma unroll
    for (int ni = 0; ni < 16; ni++) {
        int row = bm * 64 + nz * 16 + ni;
        if (row < N_NODES) P[(size_t)row * 64 + f] = acc[ni];
    }
}

// one wave per dst node; lane = feature. Fused self-term + bias + BN + ReLU.
__global__ __launch_bounds__(256) void gather_kernel(const float* __restrict__ P,
                                                     const int2* __restrict__ epk,
                                                     const int* __restrict__ offs,
                                                     const float* __restrict__ dinv,
                                                     const float* __restrict__ bias,
                                                     const float* __restrict__ gm, const float* __restrict__ bt,
                                                     const float* __restrict__ mn, const float* __restrict__ vr,
                                                     float* __restrict__ H) {
    int node = blockIdx.x * 4 + (threadIdx.x >> 6);  // 25000*4 == N_NODES exact
    int f = threadIdx.x & 63;
    float di = dinv[node];
    int beg = offs[node], end = offs[node + 1];
    float acc0 = P[(size_t)node * 64 + f] * di * di;
    float acc1 = 0.f;
    int i = beg;
    for (; i + 1 < end; i += 2) {
        int2 e0 = epk[i], e1 = epk[i + 1];
        acc0 += P[(size_t)e0.x * 64 + f] * __int_as_float(e0.y);
        acc1 += P[(size_t)e1.x * 64 + f] * __int_as_float(e1.y);
    }
    if (i < end) {
        int2 e0 = epk[i];
        acc0 += P[(size_t)e0.x * 64 + f] * __int_as_float(e0.y);
    }
    float vv = acc0 + acc1 + bias[f];
    float s = gm[f] * rsqrtf(vr[f] + EPSV);
    vv = (vv - mn[f]) * s + bt[f];
    H[(size_t)node * 64 + f] = fmaxf(vv, 0.f);
}

__global__ __launch_bounds__(256) void pool_kernel(const float* __restrict__ H,
                                                   const int* __restrict__ batch,
                                                   float* __restrict__ emb) {
    int g = blockIdx.x, tid = threadIdx.x;
    int lo = 0, hi = N_NODES;
    while (lo < hi) { int mid = (lo + hi) >> 1; if (batch[mid] < g) lo = mid + 1; else hi = mid; }
    int start = lo;
    hi = N_NODES;
    while (lo < hi) { int mid = (lo + hi) >> 1; if (batch[mid] < g + 1) lo = mid + 1; else hi = mid; }
    int end = lo;
    int f = tid & 63, p = tid >> 6;
    float acc = 0.f;
    for (int n = start + p; n < end; n += 4) acc += H[(size_t)n * 64 + f];
    __shared__ float sm[4][64];
    sm[p][f] = acc;
    __syncthreads();
    if (p == 0) {
        float tot = sm[0][f] + sm[1][f] + sm[2][f] + sm[3][f];
        emb[g * 64 + f] = tot / fmaxf((float)(end - start), 1.f);
    }
}

// ---------------- LSTM ----------------

__global__ __launch_bounds__(512, 2) void lstm0_kernel(const float* __restrict__ dyn,
                                                       const float* __restrict__ Wih,
                                                       const float* __restrict__ Whh,
                                                       const float* __restrict__ bih,
                                                       const float* __restrict__ bhh,
                                                       float* __restrict__ H0) {
    int b = blockIdx.x, g = threadIdx.x, lane = g & 63;
    float w[128];
    const float4* W4 = (const float4*)(Whh + (size_t)g * 128);
#pragma unroll
    for (int i = 0; i < 32; i++) {
        float4 v = W4[i];
        w[4 * i] = v.x; w[4 * i + 1] = v.y; w[4 * i + 2] = v.z; w[4 * i + 3] = v.w;
    }
    float wx[16];
    const float4* Wx4 = (const float4*)(Wih + (size_t)g * 16);
#pragma unroll
    for (int i = 0; i < 4; i++) {
        float4 v = Wx4[i];
        wx[4 * i] = v.x; wx[4 * i + 1] = v.y; wx[4 * i + 2] = v.z; wx[4 * i + 3] = v.w;
    }
    float bias = bih[g] + bhh[g];
    __shared__ float h_s[128];
    __shared__ float z_s[512];
    float c = 0.f;
    if (g < 128) h_s[g] = 0.f;
    __syncthreads();
    const float* xb = dyn + (size_t)b * SEQ * F_DYN;
    float* Hb = H0 + (size_t)b * SEQ * 128;
    float xtv = xb[lane & 15];
    for (int t = 0; t < SEQ; t++) {
        float xtn = (t + 1 < SEQ) ? xb[(t + 1) * 16 + (lane & 15)] : 0.f;
        float hva = h_s[lane], hvb = h_s[64 + lane];
        float a0 = bias, a1 = 0.f, a2 = 0.f, a3 = 0.f;
#pragma unroll
        for (int k = 0; k < 16; k += 4) {
            a0 += wx[k] * rl(xtv, k);
            a1 += wx[k + 1] * rl(xtv, k + 1);
            a2 += wx[k + 2] * rl(xtv, k + 2);
            a3 += wx[k + 3] * rl(xtv, k + 3);
        }
#pragma unroll
        for (int k = 0; k < 64; k += 4) {
            a0 += w[k] * rl(hva, k);
            a1 += w[k + 1] * rl(hva, k + 1);
            a2 += w[k + 2] * rl(hva, k + 2);
            a3 += w[k + 3] * rl(hva, k + 3);
        }
#pragma unroll
        for (int k = 0; k < 64; k += 4) {
            a0 += w[64 + k] * rl(hvb, k);
            a1 += w[65 + k] * rl(hvb, k + 1);
            a2 += w[66 + k] * rl(hvb, k + 2);
            a3 += w[67 + k] * rl(hvb, k + 3);
        }
        z_s[g] = (a0 + a1) + (a2 + a3);
        __syncthreads();
        if (g < 128) {
            float zi = z_s[g], zf = z_s[g + 128], zg = z_s[g + 256], zo = z_s[g + 384];
            float ii = sigmoidf_(zi), ff = sigmoidf_(zf), gg = tanhf_(zg), oo = sigmoidf_(zo);
            c = ff * c + ii * gg;
            float hn = oo * tanhf_(c);
            h_s[g] = hn;
            Hb[t * 128 + g] = hn;
        }
        __syncthreads();
        xtv = xtn;
    }
}

__global__ __launch_bounds__(256, 2) void gemm_a1_kernel(const float* __restrict__ H0,
                                                         const float* __restrict__ B,
                                                         const float* __restrict__ bih,
                                                         const float* __restrict__ bhh,
                                                         float* __restrict__ A1c, int t0) {
    __shared__ float As[64][132];
    __shared__ float Bs[64][132];
    int tid = threadIdx.x;
    int bm = blockIdx.x, bn = blockIdx.y;
    int tx = tid & 15, ty = tid >> 4;
    float acc[8][8];
#pragma unroll
    for (int i = 0; i < 8; i++)
#pragma unroll
        for (int j = 0; j < 8; j++) acc[i][j] = 0.f;
    for (int kc = 0; kc < 128; kc += 64) {
#pragma unroll
        for (int i = 0; i < 8; i++) {
            int f4 = i * 256 + tid;
            int r = f4 >> 4;
            int cc = (f4 & 15) * 4;
            int row = bm * 128 + r;
            int bb = row / TC, tl = row - bb * TC;
            int t = t0 + tl;
            float4 v = make_float4(0.f, 0.f, 0.f, 0.f);
            if (t < SEQ) v = *(const float4*)(H0 + ((size_t)bb * SEQ + t) * 128 + kc + cc);
            As[cc + 0][r] = v.x; As[cc + 1][r] = v.y; As[cc + 2][r] = v.z; As[cc + 3][r] = v.w;
            float4 u = *(const float4*)(B + (size_t)(bn * 128 + r) * 128 + kc + cc);
            Bs[cc + 0][r] = u.x; Bs[cc + 1][r] = u.y; Bs[cc + 2][r] = u.z; Bs[cc + 3][r] = u.w;
        }
        __syncthreads();
#pragma unroll
        for (int k = 0; k < 64; k++) {
            float av[8], bv[8];
            *(float4*)&av[0] = *(const float4*)&As[k][ty * 8];
            *(float4*)&av[4] = *(const float4*)&As[k][ty * 8 + 4];
            *(float4*)&bv[0] = *(const float4*)&Bs[k][tx * 8];
            *(float4*)&bv[4] = *(const float4*)&Bs[k][tx * 8 + 4];
#pragma unroll
            for (int i = 0; i < 8; i++)
#pragma unroll
                for (int j = 0; j < 8; j++) acc[i][j] += av[i] * bv[j];
        }
        __syncthreads();
    }
    float bb8[8];
#pragma unroll
    for (int j = 0; j < 8; j++) {
        int col = bn * 128 + tx * 8 + j;
        bb8[j] = bih[col] + bhh[col];
    }
#pragma unroll
    for (int i = 0; i < 8; i++) {
        int row = bm * 128 + ty * 8 + i;
        float4 o0 = make_float4(acc[i][0] + bb8[0], acc[i][1] + bb8[1], acc[i][2] + bb8[2], acc[i][3] + bb8[3]);
        float4 o1 = make_float4(acc[i][4] + bb8[4], acc[i][5] + bb8[5], acc[i][6] + bb8[6], acc[i][7] + bb8[7]);
        *(float4*)(A1c + (size_t)row * GATES + bn * 128 + tx * 8) = o0;
        *(float4*)(A1c + (size_t)row * GATES + bn * 128 + tx * 8 + 4) = o1;
    }
}

__global__ __launch_bounds__(512, 2) void lstm1_kernel(const float* __restrict__ A1c,
                                                       const float* __restrict__ Whh,
                                                       float* __restrict__ state,
                                                       float* __restrict__ rnn, int t0, int tc) {
    int b = blockIdx.x, g = threadIdx.x, lane = g & 63;
    float w[128];
    const float4* W4 = (const float4*)(Whh + (size_t)g * 128);
#pragma unroll
    for (int i = 0; i < 32; i++) {
        float4 v = W4[i];
        w[4 * i] = v.x; w[4 * i + 1] = v.y; w[4 * i + 2] = v.z; w[4 * i + 3] = v.w;
    }
    __shared__ float h_s[128];
    __shared__ float z_s[512];
    float c = 0.f;
    if (g < 128) {
        if (t0 == 0) {
            h_s[g] = 0.f;
        } else {
            h_s[g] = state[b * 128 + g];
            c = state[N_GRAPHS * 128 + b * 128 + g];
        }
    }
    __syncthreads();
    const float* Ab = A1c + (size_t)b * TC * GATES;
    float a_cur = Ab[g];
    float hn = 0.f;
    for (int tl = 0; tl < tc; tl++) {
        float a_next = (tl + 1 < tc) ? Ab[(tl + 1) * GATES + g] : 0.f;
        float hva = h_s[lane], hvb = h_s[64 + lane];
        float a0 = a_cur, a1 = 0.f, a2 = 0.f, a3 = 0.f;
#pragma unroll
        for (int k = 0; k < 64; k += 4) {
            a0 += w[k] * rl(hva, k);
            a1 += w[k + 1] * rl(hva, k + 1);
            a2 += w[k + 2] * rl(hva, k + 2);
            a3 += w[k + 3] * rl(hva, k + 3);
        }
#pragma unroll
        for (int k = 0; k < 64; k += 4) {
            a0 += w[64 + k] * rl(hvb, k);
            a1 += w[65 + k] * rl(hvb, k + 1);
            a2 += w[66 + k] * rl(hvb, k + 2);
            a3 += w[67 + k] * rl(hvb, k + 3);
        }
        z_s[g] = (a0 + a1) + (a2 + a3);
        __syncthreads();
        if (g < 128) {
            float zi = z_s[g], zf = z_s[g + 128], zg = z_s[g + 256], zo = z_s[g + 384];
            float ii = sigmoidf_(zi), ff = sigmoidf_(zf), gg = tanhf_(zg), oo = sigmoidf_(zo);
            c = ff * c + ii * gg;
            hn = oo * tanhf_(c);
            h_s[g] = hn;
        }
        __syncthreads();
        a_cur = a_next;
    }
    if (g < 128) {
        state[b * 128 + g] = hn;
        state[N_GRAPHS * 128 + b * 128 + g] = c;
        if (t0 + tc == SEQ) rnn[b * 128 + g] = hn;
    }
}

// ---------------- Head ----------------

__global__ __launch_bounds__(128) void head_kernel(const float* __restrict__ gnn, const float* __restrict__ rnn,
                                                   const float* __restrict__ Wf1, const float* __restrict__ bf1,
                                                   const float* __restrict__ fg, const float* __restrict__ fb,
                                                   const float* __restrict__ fm, const float* __restrict__ fv,
                                                   const float* __restrict__ Wf2, const float* __restrict__ bf2,
                                                   const float* __restrict__ Wo, const float* __restrict__ bo,
                                                   float* __restrict__ out) {
    int b = blockIdx.x, tid = threadIdx.x;
    __shared__ float fused[192];
    __shared__ float x1[128];
    __shared__ float x2[64];
    if (tid < 64) fused[tid] = gnn[b * 64 + tid];
    fused[64 + tid] = rnn[b * 128 + tid];
    __syncthreads();
    float acc = bf1[tid];
    for (int k = 0; k < 192; k++) acc += fused[k] * Wf1[k * 128 + tid];
    float s = fg[tid] * rsqrtf(fv[tid] + EPSV);
    acc = (acc - fm[tid]) * s + fb[tid];
    x1[tid] = fmaxf(acc, 0.f);
    __syncthreads();
    if (tid < 64) {
        float a2 = bf2[tid];
        for (int k = 0; k < 128; k++) a2 += x1[k] * Wf2[k * 64 + tid];
        x2[tid] = fmaxf(a2, 0.f);
    }
    __syncthreads();
    if (tid < 10) {
        float a3 = bo[tid];
        for (int k = 0; k < 64; k++) a3 += x2[k] * Wo[k * 10 + tid];
        out[b * 10 + tid] = a3;
    }
}

extern "C" void kernel_launch(void* const* d_in, const int* in_sizes, int n_in,
                              void* d_out, int out_size, void* d_ws, size_t ws_size,
                              hipStream_t stream) {
    const float* dyn = (const float*)d_in[0];
    const float* xs = (const float*)d_in[1];
    const int* ei = (const int*)d_in[2];
    const int* batch = (const int*)d_in[3];
    const float* Wg1 = (const float*)d_in[4];
    const float* bg1 = (const float*)d_in[5];
    const float* Wg2 = (const float*)d_in[6];
    const float* bg2 = (const float*)d_in[7];
    const float* bn1g = (const float*)d_in[8], *bn1b = (const float*)d_in[9];
    const float* bn1m = (const float*)d_in[10], *bn1v = (const float*)d_in[11];
    const float* bn2g = (const float*)d_in[12], *bn2b = (const float*)d_in[13];
    const float* bn2m = (const float*)d_in[14], *bn2v = (const float*)d_in[15];
    const float* l0Wih = (const float*)d_in[16], *l0Whh = (const float*)d_in[17];
    const float* l0bih = (const float*)d_in[18], *l0bhh = (const float*)d_in[19];
    const float* l1Wih = (const float*)d_in[20], *l1Whh = (const float*)d_in[21];
    const float* l1bih = (const float*)d_in[22], *l1bhh = (const float*)d_in[23];
    const float* Wf1 = (const float*)d_in[24], *bf1 = (const float*)d_in[25];
    const float* fbg = (const float*)d_in[26], *fbb = (const float*)d_in[27];
    const float* fbm = (const float*)d_in[28], *fbv = (const float*)d_in[29];
    const float* Wf2 = (const float*)d_in[30], *bf2 = (const float*)d_in[31];
    const float* Wo = (const float*)d_in[32], *bo = (const float*)d_in[33];
    float* out = (float*)d_out;

    float* ws = (float*)d_ws;
    float* P = ws;                      // 6,400,000 f
    float* H = P + 6400000;             // 6,400,000 f
    float* dinv = H + 6400000;          // 100,000 f
    float* gnn = dinv + 100000;         // 16,384 f
    float* rnn = gnn + 16384;           // 32,768 f
    float* st = rnn + 32768;            // 65,536 f (h1 ; c1)
    float* H0 = st + 65536;             // 11,962,880 f
    float* A1c = H0 + 11962880;         // 6,291,456 f
    int* deg = (int*)(A1c + 6291456);   // 100,096 i
    int* offs = deg + 100096;           // 100,001 i
    int* cursor = offs + 100001;        // 100,000 i (+pad 1)
    int* bsum = cursor + 100001;        // 512 i
    int2* epk = (int2*)(bsum + 512);    // 1,600,000 int2  — total ≈ 139 MB

    // ---- CSR build (shared by both GCN layers) ----
    hipMemsetAsync(deg, 0, N_NODES * sizeof(int), stream);
    hist_kernel<<<(N_EDGES + 255) / 256, 256, 0, stream>>>(ei, deg);
    scan1_kernel<<<NBLK_SCAN, 256, 0, stream>>>(deg, bsum);
    scan2_kernel<<<1, 512, 0, stream>>>(bsum);
    scan3_kernel<<<NBLK_SCAN, 256, 0, stream>>>(deg, bsum, offs, cursor, dinv);
    fill_kernel<<<(N_EDGES + 255) / 256, 256, 0, stream>>>(ei, dinv, cursor, epk);

    // ---- GCN layer 1 ----
    mm_kernel<32><<<(N_NODES + 63) / 64, 256, 0, stream>>>(xs, Wg1, P);
    gather_kernel<<<N_NODES / 4, 256, 0, stream>>>(P, epk, offs, dinv, bg1, bn1g, bn1b, bn1m, bn1v, H);
    // ---- GCN layer 2 ----
    mm_kernel<64><<<(N_NODES + 63) / 64, 256, 0, stream>>>(H, Wg2, P);
    gather_kernel<<<N_NODES / 4, 256, 0, stream>>>(P, epk, offs, dinv, bg2, bn2g, bn2b, bn2m, bn2v, H);

    pool_kernel<<<N_GRAPHS, 256, 0, stream>>>(H, batch, gnn);

    lstm0_kernel<<<N_GRAPHS, 512, 0, stream>>>(dyn, l0Wih, l0Whh, l0bih, l0bhh, H0);
    for (int ch = 0; ch < NCHUNK; ch++) {
        int t0 = ch * TC;
        int tc = (SEQ - t0 < TC) ? (SEQ - t0) : TC;
        gemm_a1_kernel<<<dim3(96, 4), 256, 0, stream>>>(H0, l1Wih, l1bih, l1bhh, A1c, t0);
        lstm1_kernel<<<N_GRAPHS, 512, 0, stream>>>(A1c, l1Whh, st, rnn, t0, tc);
    }

    head_kernel<<<N_GRAPHS, 128, 0, stream>>>(gnn, rnn, Wf1, bf1, fbg, fbb, fbm, fbv, Wf2, bf2, Wo, bo, out);
}